// Round 4
// baseline (266.269 us; speedup 1.0000x reference)
//
#include <hip/hip_runtime.h>
#include <math.h>

// Tropical bottleneck network, fp32.
// Activations in chunked-transposed layout [K/4][1024][4]: lane = batch b,
// float4 loads/stores coalesced. Weights W[i][k] wave-uniform -> forced to
// the SCALAR path via readfirstlane (s_load_dwordx4, no VALU addressing).
//
// tsemi: 512 threads = 8 waves = 2 row-waves (4 rows each) x 4 K-quarters
// (intra-block K-split, LDS combine). Block = 8 output rows x 64 batch.

#define BALL 1024

struct Job {
    const float* X;    // chunked [K/4][1024][4]
    const float* W;    // [rows][K] row-major
    const float* bias; // [rows] (max stages only)
    const float* E1;   // chunked, min-combine, or nullptr
    const float* E2;   // chunked, max-combine, or nullptr
    float* Y;          // chunked [rows/4][1024][4]
    int K;
};

template<int IS_MAX>
__device__ __forceinline__ void corequad(
    const float4* __restrict__ Xb,   // X4 + b ; stride BALL float4s per chunk
    const float4* __restrict__ w0, const float4* __restrict__ w1,
    const float4* __restrict__ w2, const float4* __restrict__ w3,
    int kcB, int kcE, float& a0, float& a1, float& a2, float& a3)
{
#define RD(x, y) (IS_MAX ? fmaxf((x), (y)) : fminf((x), (y)))
    {   // peel first chunk: initializes accumulators, no +-INF
        float4 xv = Xb[(size_t)kcB * BALL];
        float4 w;
        w = w0[kcB]; a0 = RD(RD(xv.x + w.x, xv.y + w.y), RD(xv.z + w.z, xv.w + w.w));
        w = w1[kcB]; a1 = RD(RD(xv.x + w.x, xv.y + w.y), RD(xv.z + w.z, xv.w + w.w));
        w = w2[kcB]; a2 = RD(RD(xv.x + w.x, xv.y + w.y), RD(xv.z + w.z, xv.w + w.w));
        w = w3[kcB]; a3 = RD(RD(xv.x + w.x, xv.y + w.y), RD(xv.z + w.z, xv.w + w.w));
    }
#pragma unroll 4
    for (int kc = kcB + 1; kc < kcE; ++kc) {
        float4 xv = Xb[(size_t)kc * BALL];
        float4 w;
        // chain fuses to v_min3/v_max3: min3(t0,t1,t2) then min3(m,t3,acc)
        w = w0[kc]; a0 = RD(RD(RD(RD(xv.x + w.x, xv.y + w.y), xv.z + w.z), xv.w + w.w), a0);
        w = w1[kc]; a1 = RD(RD(RD(RD(xv.x + w.x, xv.y + w.y), xv.z + w.z), xv.w + w.w), a1);
        w = w2[kc]; a2 = RD(RD(RD(RD(xv.x + w.x, xv.y + w.y), xv.z + w.z), xv.w + w.w), a2);
        w = w3[kc]; a3 = RD(RD(RD(RD(xv.x + w.x, xv.y + w.y), xv.z + w.z), xv.w + w.w), a3);
    }
#undef RD
}

// Two jobs per launch: blocks with blockIdx.y < nbyA run ja, the rest jb.
template<int IS_MAX>
__global__ __launch_bounds__(512) void tsemi(Job ja, Job jb, int nbyA)
{
    __shared__ float part[3][8][64];
    int by = blockIdx.y;
    Job j = ja;
    if (by >= nbyA) { j = jb; by -= nbyA; }

    const int lane = threadIdx.x & 63;
    const int wv   = threadIdx.x >> 6;   // 0..7
    const int rw   = wv & 1;             // row-wave (0..1)
    const int q    = wv >> 1;            // K-quarter (0..3)
    const int b    = blockIdx.x * 64 + lane;
    // force the row index into an SGPR so W/bias loads take the scalar path
    const int i0   = __builtin_amdgcn_readfirstlane(by * 8 + rw * 4);

    const int K   = j.K;
    const int CQ  = K >> 4;              // chunks per quarter = (K/4)/4
    const int kcB = q * CQ;
    const int kcE = kcB + CQ;

    const float4* Xb = (const float4*)j.X + b;
    const float4* w0 = (const float4*)(j.W + (size_t)(i0 + 0) * K);
    const float4* w1 = (const float4*)(j.W + (size_t)(i0 + 1) * K);
    const float4* w2 = (const float4*)(j.W + (size_t)(i0 + 2) * K);
    const float4* w3 = (const float4*)(j.W + (size_t)(i0 + 3) * K);

    float a0, a1, a2, a3;
    corequad<IS_MAX>(Xb, w0, w1, w2, w3, kcB, kcE, a0, a1, a2, a3);

    if (q) {
        part[q - 1][rw * 4 + 0][lane] = a0;
        part[q - 1][rw * 4 + 1][lane] = a1;
        part[q - 1][rw * 4 + 2][lane] = a2;
        part[q - 1][rw * 4 + 3][lane] = a3;
    }
    __syncthreads();
    if (q == 0) {
#define RD(x, y) (IS_MAX ? fmaxf((x), (y)) : fminf((x), (y)))
#pragma unroll
        for (int qq = 0; qq < 3; ++qq) {
            a0 = RD(a0, part[qq][rw * 4 + 0][lane]);
            a1 = RD(a1, part[qq][rw * 4 + 1][lane]);
            a2 = RD(a2, part[qq][rw * 4 + 2][lane]);
            a3 = RD(a3, part[qq][rw * 4 + 3][lane]);
        }
#undef RD
        if (IS_MAX) {
            const float4 bb = *(const float4*)(j.bias + i0);
            a0 += bb.x; a1 += bb.y; a2 += bb.z; a3 += bb.w;
        }
        if (j.E1) {
            float4 e = ((const float4*)j.E1)[(size_t)(i0 >> 2) * BALL + b];
            a0 = fminf(a0, e.x); a1 = fminf(a1, e.y);
            a2 = fminf(a2, e.z); a3 = fminf(a3, e.w);
        }
        if (j.E2) {
            float4 e = ((const float4*)j.E2)[(size_t)(i0 >> 2) * BALL + b];
            a0 = fmaxf(a0, e.x); a1 = fmaxf(a1, e.y);
            a2 = fmaxf(a2, e.z); a3 = fmaxf(a3, e.w);
        }
        ((float4*)j.Y)[(size_t)(i0 >> 2) * BALL + b] = make_float4(a0, a1, a2, a3);
    }
}

// x [1024][256] -> Xc chunked [64][1024][4]
__global__ __launch_bounds__(256) void t_in(const float* __restrict__ x,
                                            float* __restrict__ Xc)
{
    __shared__ float s[64][65];
    const int lane = threadIdx.x & 63;
    const int ty   = threadIdx.x >> 6;  // 0..3
    const int b0   = blockIdx.x * 64;
    const int k0   = blockIdx.y * 64;
#pragma unroll
    for (int r = ty; r < 64; r += 4)
        s[r][lane] = x[(size_t)(b0 + r) * 256 + k0 + lane];
    __syncthreads();
    float4* X4 = (float4*)Xc;
#pragma unroll
    for (int cc = 0; cc < 4; ++cc) {
        int c = ty * 4 + cc;  // chunk within tile, 0..15
        float4 v = make_float4(s[lane][c * 4 + 0], s[lane][c * 4 + 1],
                               s[lane][c * 4 + 2], s[lane][c * 4 + 3]);
        X4[(size_t)(k0 / 4 + c) * BALL + b0 + lane] = v;
    }
}

// Zc chunked [128][1024][4] (512 rows) -> out [1024][512]
__global__ __launch_bounds__(256) void t_out(const float* __restrict__ Zc,
                                             float* __restrict__ out)
{
    __shared__ float s[64][65];
    const int lane = threadIdx.x & 63;
    const int ty   = threadIdx.x >> 6;
    const int i0   = blockIdx.x * 64;
    const int b0   = blockIdx.y * 64;
    const float4* Z4 = (const float4*)Zc;
#pragma unroll
    for (int cc = 0; cc < 4; ++cc) {
        int c = ty * 4 + cc;
        float4 v = Z4[(size_t)(i0 / 4 + c) * BALL + b0 + lane];
        s[lane][c * 4 + 0] = v.x; s[lane][c * 4 + 1] = v.y;
        s[lane][c * 4 + 2] = v.z; s[lane][c * 4 + 3] = v.w;
    }
    __syncthreads();
#pragma unroll
    for (int r = ty; r < 64; r += 4)
        out[(size_t)(b0 + r) * 512 + i0 + lane] = s[r][lane];
}

extern "C" void kernel_launch(void* const* d_in, const int* in_sizes, int n_in,
                              void* d_out, int out_size, void* d_ws, size_t ws_size,
                              hipStream_t stream) {
    const float* x      = (const float*)d_in[0];
    const float* l1_w1  = (const float*)d_in[1];
    const float* l1_w2  = (const float*)d_in[2];
    const float* l1_b2  = (const float*)d_in[3];
    const float* l2_w1  = (const float*)d_in[4];
    const float* l2_w2  = (const float*)d_in[5];
    const float* l2_b2  = (const float*)d_in[6];
    const float* l3_w1  = (const float*)d_in[7];
    const float* l3_w2  = (const float*)d_in[8];
    const float* l3_b2  = (const float*)d_in[9];
    const float* l4_w1  = (const float*)d_in[10];
    const float* l4_w2  = (const float*)d_in[11];
    const float* l4_b2  = (const float*)d_in[12];
    const float* l4_sw1 = (const float*)d_in[13];
    const float* l4_sw2 = (const float*)d_in[14];
    const float* l4_sb2 = (const float*)d_in[15];
    const float* sc_w1  = (const float*)d_in[16];
    const float* sc_w2  = (const float*)d_in[17];
    const float* sc_b2  = (const float*)d_in[18];
    (void)in_sizes; (void)n_in; (void)ws_size; (void)out_size;

    float* out = (float*)d_out;
    float* ws  = (float*)d_ws;

    const int IN = 256, OUT = 512;

    // workspace (floats), 7.0 MB peak:
    float* Xc    = ws;             // 1 MB  (x chunked; later reused as X2)
    float* M     = ws + 262144;    // 1 MB
    float* A     = ws + 524288;    // 1 MB
    float* SC0   = ws + 786432;    // 2 MB
    float* SCout = ws + 1310720;   // 2 MB
    // lifetime-disjoint aliases:
    float* X2 = Xc;                // layer-2 output (Xc dead after stage 3)
    float* T  = SC0;               // layer-4 main pre-act (SC0 dead after stage 3)
    float* T2 = ws;                // layer-4 shortcut pre-act, 2 MB over [Xc,M] (dead after s7)
    float* Zf = SC0;               // final chunked result (T dead after stage 9)
    float* O4 = out;               // d_out doubles as scratch for layer-4 main output

    dim3 blk(512);
    Job nj{nullptr, nullptr, nullptr, nullptr, nullptr, nullptr, 0};

    // 1. x -> chunked Xc
    t_in<<<dim3(16, 4), 256, 0, stream>>>(x, Xc);

    // 2. merged min-plus: {Xc,l1_w1 -> M (256r)} + {Xc,sc_w1 -> SC0 (512r)}
    tsemi<0><<<dim3(16, 96), blk, 0, stream>>>(
        Job{Xc, l1_w1, nullptr, nullptr, nullptr, M, IN},
        Job{Xc, sc_w1, nullptr, nullptr, nullptr, SC0, IN}, 32);

    // 3. merged max-plus: {M,l1_w2,b2, min Xc -> A} + {SC0,sc_w2,sc_b2 -> SCout}
    tsemi<1><<<dim3(16, 96), blk, 0, stream>>>(
        Job{M, l1_w2, l1_b2, Xc, nullptr, A, IN},
        Job{SC0, sc_w2, sc_b2, nullptr, nullptr, SCout, OUT}, 32);

    // 4-7. layers 2 and 3
    tsemi<0><<<dim3(16, 32), blk, 0, stream>>>(
        Job{A, l2_w1, nullptr, nullptr, nullptr, M, IN}, nj, 32);
    tsemi<1><<<dim3(16, 32), blk, 0, stream>>>(
        Job{M, l2_w2, l2_b2, A, nullptr, X2, IN}, nj, 32);
    tsemi<0><<<dim3(16, 32), blk, 0, stream>>>(
        Job{X2, l3_w1, nullptr, nullptr, nullptr, M, IN}, nj, 32);
    tsemi<1><<<dim3(16, 32), blk, 0, stream>>>(
        Job{M, l3_w2, l3_b2, X2, nullptr, A, IN}, nj, 32);   // A = x3

    // 8. merged layer-4 min-plus: {A,l4_w1 -> T} + {A,l4_sw1 -> T2}  (512r each)
    tsemi<0><<<dim3(16, 128), blk, 0, stream>>>(
        Job{A, l4_w1,  nullptr, nullptr, nullptr, T,  IN},
        Job{A, l4_sw1, nullptr, nullptr, nullptr, T2, IN}, 64);

    // 9. layer-4 main max-plus -> O4 (staged in d_out, chunked)
    tsemi<1><<<dim3(16, 64), blk, 0, stream>>>(
        Job{T, l4_w2, l4_b2, nullptr, nullptr, O4, OUT}, nj, 64);

    // 10. layer-4 shortcut max-plus, min with O4, max with SCout -> Zf
    tsemi<1><<<dim3(16, 64), blk, 0, stream>>>(
        Job{T2, l4_sw2, l4_sb2, O4, SCout, Zf, OUT}, nj, 64);

    // 11. un-transpose Zf -> out
    t_out<<<dim3(8, 16), 256, 0, stream>>>(Zf, out);
}

// Round 5
// 110.023 us; speedup vs baseline: 2.4201x; 2.4201x over previous
//
#include <hip/hip_runtime.h>
#include <math.h>

// Tropical bottleneck network, fp32.
// Activations in chunked-transposed layout [K/4][1024][4]: lane = batch b,
// float4 loads/stores coalesced. Weights are staged into LDS once per block
// and read with wave-uniform ds_read_b128 (broadcast, conflict-free, in-order
// -> compiler pipelines with fine-grained lgkmcnt). No SMEM in the hot loop.
//
// tsemi: 512 threads = 8 waves = 2 row-waves (8 rows each) x 4 K-quarters
// (intra-block K-split, LDS combine). Block = 16 output rows x 64 batch.

#define BALL 1024

struct Job {
    const float* X;    // chunked [K/4][1024][4]
    const float* W;    // [rows][K] row-major
    const float* bias; // [rows] (max stages only)
    const float* E1;   // chunked, min-combine, or nullptr
    const float* E2;   // chunked, max-combine, or nullptr
    float* Y;          // chunked [rows/4][1024][4]
};

template<int IS_MAX, int K>
__device__ __forceinline__ void run_job(
    const Job j, int by, float4* __restrict__ Wl4,
    float (* __restrict__ part)[16][64])
{
    const int tid  = threadIdx.x;
    const int lane = tid & 63;
    const int wv   = tid >> 6;      // 0..7
    const int rw   = wv & 1;        // row-wave
    const int q    = wv >> 1;       // K-quarter
    const int b    = blockIdx.x * 64 + lane;
    const int i0   = by * 16;       // block's base output row
    const int r0   = rw * 8;        // this wave's row offset within block

#define RD(x, y) (IS_MAX ? fmaxf((x), (y)) : fminf((x), (y)))

    // ---- stage W[16 rows][K] into LDS (coalesced float4) ----
    const float4* Wg = (const float4*)(j.W + (size_t)i0 * K);
    constexpr int NW4 = 16 * K / 4;       // 1024 (K=256) or 2048 (K=512)
#pragma unroll
    for (int idx = 0; idx < NW4; idx += 512)
        Wl4[idx + tid] = Wg[idx + tid];
    __syncthreads();

    // ---- K-quarter reduction, 8 rows per wave ----
    constexpr int CQ  = K / 16;           // chunks per quarter
    const int kcB = q * CQ;
    const float4* Xb = (const float4*)j.X + b;
    const float4* wrow = Wl4 + (size_t)r0 * (K / 4);

    float acc[8];
    {   // peel first chunk (initializes accumulators, no +-INF)
        float4 xv = Xb[(size_t)kcB * BALL];
#pragma unroll
        for (int r = 0; r < 8; ++r) {
            float4 w = wrow[r * (K / 4) + kcB];
            acc[r] = RD(RD(xv.x + w.x, xv.y + w.y), RD(xv.z + w.z, xv.w + w.w));
        }
    }
#pragma unroll 4
    for (int kc = kcB + 1; kc < kcB + CQ; ++kc) {
        float4 xv = Xb[(size_t)kc * BALL];
#pragma unroll
        for (int r = 0; r < 8; ++r) {
            float4 w = wrow[r * (K / 4) + kc];
            // fuses to v_min3/v_max3: (t0,t1,t2) then (m,t3,acc)
            acc[r] = RD(RD(RD(RD(xv.x + w.x, xv.y + w.y), xv.z + w.z), xv.w + w.w), acc[r]);
        }
    }

    // ---- combine quarters via LDS ----
    if (q) {
#pragma unroll
        for (int r = 0; r < 8; ++r) part[q - 1][r0 + r][lane] = acc[r];
    }
    __syncthreads();
    if (q == 0) {
#pragma unroll
        for (int qq = 0; qq < 3; ++qq)
#pragma unroll
            for (int r = 0; r < 8; ++r)
                acc[r] = RD(acc[r], part[qq][r0 + r][lane]);

        const int c0 = (i0 + r0) >> 2;    // output chunk index (2 chunks: c0, c0+1)
        if (IS_MAX) {
            float4 b0 = ((const float4*)j.bias)[c0];
            float4 b1 = ((const float4*)j.bias)[c0 + 1];
            acc[0] += b0.x; acc[1] += b0.y; acc[2] += b0.z; acc[3] += b0.w;
            acc[4] += b1.x; acc[5] += b1.y; acc[6] += b1.z; acc[7] += b1.w;
        }
        if (j.E1) {
            float4 e0 = ((const float4*)j.E1)[(size_t)c0 * BALL + b];
            float4 e1 = ((const float4*)j.E1)[(size_t)(c0 + 1) * BALL + b];
            acc[0] = fminf(acc[0], e0.x); acc[1] = fminf(acc[1], e0.y);
            acc[2] = fminf(acc[2], e0.z); acc[3] = fminf(acc[3], e0.w);
            acc[4] = fminf(acc[4], e1.x); acc[5] = fminf(acc[5], e1.y);
            acc[6] = fminf(acc[6], e1.z); acc[7] = fminf(acc[7], e1.w);
        }
        if (j.E2) {
            float4 e0 = ((const float4*)j.E2)[(size_t)c0 * BALL + b];
            float4 e1 = ((const float4*)j.E2)[(size_t)(c0 + 1) * BALL + b];
            acc[0] = fmaxf(acc[0], e0.x); acc[1] = fmaxf(acc[1], e0.y);
            acc[2] = fmaxf(acc[2], e0.z); acc[3] = fmaxf(acc[3], e0.w);
            acc[4] = fmaxf(acc[4], e1.x); acc[5] = fmaxf(acc[5], e1.y);
            acc[6] = fmaxf(acc[6], e1.z); acc[7] = fmaxf(acc[7], e1.w);
        }
        ((float4*)j.Y)[(size_t)c0 * BALL + b] =
            make_float4(acc[0], acc[1], acc[2], acc[3]);
        ((float4*)j.Y)[(size_t)(c0 + 1) * BALL + b] =
            make_float4(acc[4], acc[5], acc[6], acc[7]);
    }
#undef RD
}

// Two jobs per launch: blocks with blockIdx.y < nbyA run ja (K=KA), rest jb (K=KB).
template<int IS_MAX, int KA, int KB>
__global__ __launch_bounds__(512) void tsemi(Job ja, Job jb, int nbyA)
{
    constexpr int KM = (KA > KB) ? KA : KB;
    __shared__ __align__(16) float Wl[16 * KM];
    __shared__ float part[3][16][64];

    const int by = blockIdx.y;
    if (by < nbyA) run_job<IS_MAX, KA>(ja, by, (float4*)Wl, part);
    else           run_job<IS_MAX, KB>(jb, by - nbyA, (float4*)Wl, part);
}

// x [1024][256] -> Xc chunked [64][1024][4]
__global__ __launch_bounds__(256) void t_in(const float* __restrict__ x,
                                            float* __restrict__ Xc)
{
    __shared__ float s[64][65];
    const int lane = threadIdx.x & 63;
    const int ty   = threadIdx.x >> 6;  // 0..3
    const int b0   = blockIdx.x * 64;
    const int k0   = blockIdx.y * 64;
#pragma unroll
    for (int r = ty; r < 64; r += 4)
        s[r][lane] = x[(size_t)(b0 + r) * 256 + k0 + lane];
    __syncthreads();
    float4* X4 = (float4*)Xc;
#pragma unroll
    for (int cc = 0; cc < 4; ++cc) {
        int c = ty * 4 + cc;  // chunk within tile, 0..15
        float4 v = make_float4(s[lane][c * 4 + 0], s[lane][c * 4 + 1],
                               s[lane][c * 4 + 2], s[lane][c * 4 + 3]);
        X4[(size_t)(k0 / 4 + c) * BALL + b0 + lane] = v;
    }
}

// Zc chunked [128][1024][4] (512 rows) -> out [1024][512]
__global__ __launch_bounds__(256) void t_out(const float* __restrict__ Zc,
                                             float* __restrict__ out)
{
    __shared__ float s[64][65];
    const int lane = threadIdx.x & 63;
    const int ty   = threadIdx.x >> 6;
    const int i0   = blockIdx.x * 64;
    const int b0   = blockIdx.y * 64;
    const float4* Z4 = (const float4*)Zc;
#pragma unroll
    for (int cc = 0; cc < 4; ++cc) {
        int c = ty * 4 + cc;
        float4 v = Z4[(size_t)(i0 / 4 + c) * BALL + b0 + lane];
        s[lane][c * 4 + 0] = v.x; s[lane][c * 4 + 1] = v.y;
        s[lane][c * 4 + 2] = v.z; s[lane][c * 4 + 3] = v.w;
    }
    __syncthreads();
#pragma unroll
    for (int r = ty; r < 64; r += 4)
        out[(size_t)(b0 + r) * 512 + i0 + lane] = s[r][lane];
}

extern "C" void kernel_launch(void* const* d_in, const int* in_sizes, int n_in,
                              void* d_out, int out_size, void* d_ws, size_t ws_size,
                              hipStream_t stream) {
    const float* x      = (const float*)d_in[0];
    const float* l1_w1  = (const float*)d_in[1];
    const float* l1_w2  = (const float*)d_in[2];
    const float* l1_b2  = (const float*)d_in[3];
    const float* l2_w1  = (const float*)d_in[4];
    const float* l2_w2  = (const float*)d_in[5];
    const float* l2_b2  = (const float*)d_in[6];
    const float* l3_w1  = (const float*)d_in[7];
    const float* l3_w2  = (const float*)d_in[8];
    const float* l3_b2  = (const float*)d_in[9];
    const float* l4_w1  = (const float*)d_in[10];
    const float* l4_w2  = (const float*)d_in[11];
    const float* l4_b2  = (const float*)d_in[12];
    const float* l4_sw1 = (const float*)d_in[13];
    const float* l4_sw2 = (const float*)d_in[14];
    const float* l4_sb2 = (const float*)d_in[15];
    const float* sc_w1  = (const float*)d_in[16];
    const float* sc_w2  = (const float*)d_in[17];
    const float* sc_b2  = (const float*)d_in[18];
    (void)in_sizes; (void)n_in; (void)ws_size; (void)out_size;

    float* out = (float*)d_out;
    float* ws  = (float*)d_ws;

    // workspace (floats), 7.0 MB peak:
    float* Xc    = ws;             // 1 MB  (x chunked; later reused as X2)
    float* M     = ws + 262144;    // 1 MB
    float* A     = ws + 524288;    // 1 MB
    float* SC0   = ws + 786432;    // 2 MB
    float* SCout = ws + 1310720;   // 2 MB
    // lifetime-disjoint aliases:
    float* X2 = Xc;                // layer-2 output (Xc dead after stage 3)
    float* T  = SC0;               // layer-4 main pre-act (SC0 dead after stage 3)
    float* T2 = ws;                // layer-4 shortcut pre-act, 2 MB over [Xc,M]
    float* Zf = SC0;               // final chunked result (T dead after stage 9)
    float* O4 = out;               // d_out doubles as scratch (chunked)

    dim3 blk(512);
    Job nj{nullptr, nullptr, nullptr, nullptr, nullptr, nullptr};

    // 1. x -> chunked Xc
    t_in<<<dim3(16, 4), 256, 0, stream>>>(x, Xc);

    // 2. merged min-plus: {Xc,l1_w1 -> M (256r)} + {Xc,sc_w1 -> SC0 (512r)}
    tsemi<0, 256, 256><<<dim3(16, 48), blk, 0, stream>>>(
        Job{Xc, l1_w1, nullptr, nullptr, nullptr, M},
        Job{Xc, sc_w1, nullptr, nullptr, nullptr, SC0}, 16);

    // 3. merged max-plus: {M,l1_w2,b2, min Xc -> A} + {SC0,sc_w2,sc_b2 -> SCout}
    tsemi<1, 256, 512><<<dim3(16, 48), blk, 0, stream>>>(
        Job{M, l1_w2, l1_b2, Xc, nullptr, A},
        Job{SC0, sc_w2, sc_b2, nullptr, nullptr, SCout}, 16);

    // 4-7. layers 2 and 3
    tsemi<0, 256, 256><<<dim3(16, 16), blk, 0, stream>>>(
        Job{A, l2_w1, nullptr, nullptr, nullptr, M}, nj, 16);
    tsemi<1, 256, 256><<<dim3(16, 16), blk, 0, stream>>>(
        Job{M, l2_w2, l2_b2, A, nullptr, X2}, nj, 16);
    tsemi<0, 256, 256><<<dim3(16, 16), blk, 0, stream>>>(
        Job{X2, l3_w1, nullptr, nullptr, nullptr, M}, nj, 16);
    tsemi<1, 256, 256><<<dim3(16, 16), blk, 0, stream>>>(
        Job{M, l3_w2, l3_b2, X2, nullptr, A}, nj, 16);   // A = x3

    // 8. merged layer-4 min-plus: {A,l4_w1 -> T} + {A,l4_sw1 -> T2} (512r each)
    tsemi<0, 256, 256><<<dim3(16, 64), blk, 0, stream>>>(
        Job{A, l4_w1,  nullptr, nullptr, nullptr, T},
        Job{A, l4_sw1, nullptr, nullptr, nullptr, T2}, 32);

    // 9. layer-4 main max-plus -> O4 (staged in d_out, chunked)
    tsemi<1, 512, 512><<<dim3(16, 32), blk, 0, stream>>>(
        Job{T, l4_w2, l4_b2, nullptr, nullptr, O4}, nj, 32);

    // 10. layer-4 shortcut max-plus, min with O4, max with SCout -> Zf
    tsemi<1, 512, 512><<<dim3(16, 32), blk, 0, stream>>>(
        Job{T2, l4_sw2, l4_sb2, O4, SCout, Zf}, nj, 32);

    // 11. un-transpose Zf -> out
    t_out<<<dim3(8, 16), 256, 0, stream>>>(Zf, out);
}